// Round 11
// baseline (139.695 us; speedup 1.0000x reference)
//
#include <hip/hip_runtime.h>

typedef __attribute__((ext_vector_type(8))) short bf16x8;
typedef __attribute__((ext_vector_type(4))) float f32x4;
typedef __attribute__((ext_vector_type(16))) float f32x16;

#define DEV __device__ __forceinline__

static constexpr int N_TOK = 4096;
static constexpr int C     = 528;
static constexpr int NH    = 8;
static constexpr int HD    = 66;
static constexpr int HDP   = 96;    // q/k head-dim padded
static constexpr int VD96  = 96;    // v head-dim padded
static constexpr int KP    = 544;   // GEMM K padded (17*32)
static constexpr int NQKV  = 1584;
static constexpr int NQKVP = 1632;  // 17*96

DEV unsigned short f2bf(float f) {
    unsigned int u = __float_as_uint(f);
    u = (u + 0x7fffu + ((u >> 16) & 1u)) >> 16;
    return (unsigned short)u;
}
DEV float bf2f(unsigned short h) { return __uint_as_float(((unsigned int)h) << 16); }
DEV unsigned cvtpk2(float a, float b) {
    unsigned r;
    asm("v_cvt_pk_bf16_f32 %0, %1, %2" : "=v"(r) : "v"(a), "v"(b));
    return r;
}
DEV void plswap(unsigned &a, unsigned &b) {
    asm volatile("v_permlane32_swap_b32 %0, %1" : "+v"(a), "+v"(b));
}
// direct global->LDS DMA, 16B per lane; LDS dest = uniform base + lane*16 (linear)
DEV void gload16(const unsigned short* g, unsigned short* l) {
    __builtin_amdgcn_global_load_lds(
        (const __attribute__((address_space(1))) unsigned int*)(g),
        (__attribute__((address_space(3))) unsigned int*)(l), 16, 0, 0);
}

// ---------------- fused prep: xb, wqkvb, whi/wlo, qb/kb pad-zeroing ----------------
__global__ void k_prep_all(const float* __restrict__ x, const float* __restrict__ w_qkv,
                           const float* __restrict__ w_proj,
                           unsigned short* __restrict__ xb, unsigned short* __restrict__ wqkvb,
                           unsigned short* __restrict__ whi, unsigned short* __restrict__ wlo,
                           unsigned short* __restrict__ qb, unsigned short* __restrict__ kbuf) {
    const int T0 = N_TOK * KP;
    const int T1 = T0 + NQKVP * KP;
    const int T2 = T1 + KP * KP;
    const int T3 = T2 + NH * N_TOK * (HDP - HD);
    for (int idx = blockIdx.x * 256 + threadIdx.x; idx < T3; idx += gridDim.x * 256) {
        if (idx < T0) {
            int n = idx / KP, k = idx - n * KP;
            xb[idx] = (k < C) ? f2bf(x[n * C + k]) : (unsigned short)0;
        } else if (idx < T1) {
            int j = idx - T0;
            int n = j / KP, k = j - n * KP;
            wqkvb[j] = (n < NQKV && k < C) ? f2bf(w_qkv[n * C + k]) : (unsigned short)0;
        } else if (idx < T2) {
            int j = idx - T1;
            int n = j / KP, k = j - n * KP;
            unsigned short hi = 0, lo = 0;
            if (n < C && k < C) {
                float v = w_proj[n * C + k];
                hi = f2bf(v);
                lo = f2bf(v - bf2f(hi));
            }
            whi[j] = hi; wlo[j] = lo;
        } else {
            int j = idx - T2;
            int n = j / 30, p = j - 30 * n;
            size_t a = (size_t)n * HDP + HD + p;
            qb[a] = 0; kbuf[a] = 0;
        }
    }
}

// ---------------- QKV GEMM (double-buffered); epilogue scatters q/k, writes v slab ----------------
__launch_bounds__(256)
__global__ void k_gemm_qkv(const unsigned short* __restrict__ A,
                           const unsigned short* __restrict__ B,
                           const float* __restrict__ bias,
                           unsigned short* __restrict__ qb, unsigned short* __restrict__ kbuf,
                           unsigned short* __restrict__ vtmp) {
    constexpr int LDA = 40;
    __shared__ unsigned short Al[2][128 * LDA];
    __shared__ unsigned short Bl[2][96 * LDA];
    int tid = threadIdx.x, lane = tid & 63, wid = tid >> 6;
    int m0 = blockIdx.x * 128, n0 = blockIdx.y * 96;
    int wm = (wid >> 1) * 64, wn = (wid & 1) * 48;
    int arow0 = tid >> 2, arow1 = (256 + tid) >> 2, akc = (tid & 3) * 8;
    bool bhave = tid < 128;
    int brow1 = (256 + tid) >> 2;
    f32x4 acc[4][3] = {};
    bf16x8 ra0, ra1, rb0, rb1;

    ra0 = *(const bf16x8*)&A[(size_t)(m0 + arow0) * KP + akc];
    ra1 = *(const bf16x8*)&A[(size_t)(m0 + arow1) * KP + akc];
    rb0 = *(const bf16x8*)&B[(size_t)(n0 + arow0) * KP + akc];
    if (bhave) rb1 = *(const bf16x8*)&B[(size_t)(n0 + brow1) * KP + akc];
    *(bf16x8*)&Al[0][arow0 * LDA + akc] = ra0;
    *(bf16x8*)&Al[0][arow1 * LDA + akc] = ra1;
    *(bf16x8*)&Bl[0][arow0 * LDA + akc] = rb0;
    if (bhave) *(bf16x8*)&Bl[0][brow1 * LDA + akc] = rb1;
    __syncthreads();

    int kk = (lane >> 4) * 8, cc = lane & 15;
    for (int kt = 0; kt < 17; kt++) {
        int cur = kt & 1;
        if (kt < 16) {
            int k0 = (kt + 1) * 32;
            ra0 = *(const bf16x8*)&A[(size_t)(m0 + arow0) * KP + k0 + akc];
            ra1 = *(const bf16x8*)&A[(size_t)(m0 + arow1) * KP + k0 + akc];
            rb0 = *(const bf16x8*)&B[(size_t)(n0 + arow0) * KP + k0 + akc];
            if (bhave) rb1 = *(const bf16x8*)&B[(size_t)(n0 + brow1) * KP + k0 + akc];
        }
        bf16x8 af[4], bfr[3];
#pragma unroll
        for (int mi = 0; mi < 4; mi++) af[mi] = *(const bf16x8*)&Al[cur][(wm + mi * 16 + cc) * LDA + kk];
#pragma unroll
        for (int ni = 0; ni < 3; ni++) bfr[ni] = *(const bf16x8*)&Bl[cur][(wn + ni * 16 + cc) * LDA + kk];
#pragma unroll
        for (int mi = 0; mi < 4; mi++)
#pragma unroll
            for (int ni = 0; ni < 3; ni++)
                acc[mi][ni] = __builtin_amdgcn_mfma_f32_16x16x32_bf16(af[mi], bfr[ni], acc[mi][ni], 0, 0, 0);
        if (kt < 16) {
            int nxt = cur ^ 1;
            *(bf16x8*)&Al[nxt][arow0 * LDA + akc] = ra0;
            *(bf16x8*)&Al[nxt][arow1 * LDA + akc] = ra1;
            *(bf16x8*)&Bl[nxt][arow0 * LDA + akc] = rb0;
            if (bhave) *(bf16x8*)&Bl[nxt][brow1 * LDA + akc] = rb1;
        }
        __syncthreads();
    }
#pragma unroll
    for (int mi = 0; mi < 4; mi++)
#pragma unroll
        for (int ni = 0; ni < 3; ni++)
#pragma unroll
            for (int r = 0; r < 4; r++) {
                int row = m0 + wm + mi * 16 + (lane >> 4) * 4 + r;
                int col = n0 + wn + ni * 16 + cc;
                float v = acc[mi][ni][r] + (col < NQKV ? bias[col] : 0.f);
                unsigned short b = f2bf(v);
                if (col < 2 * C) {
                    int d5 = (col >= C) ? col - C : col;
                    unsigned h = (unsigned)d5 / 66u;
                    int dd = d5 - 66 * (int)h;
                    size_t a = ((size_t)h * N_TOK + row) * HDP + dd;
                    if (col >= C) kbuf[a] = b; else qb[a] = b;
                } else if (col < NQKV) {
                    vtmp[(size_t)row * C + (col - 2 * C)] = b;
                }
            }
}

// ---------------- v transpose: vtmp[4096][528] -> vt[8][96][4096] ----------------
__global__ void k_reshape_v(const unsigned short* __restrict__ vtmp, unsigned short* __restrict__ vt) {
    __shared__ unsigned short lt[64 * 104];
    int h = blockIdx.y, n0 = blockIdx.x * 64, tid = threadIdx.x;
#pragma unroll
    for (int i = 0; i < 24; i++) {
        int idx = i * 256 + tid;
        int ni = idx / 96, d = idx - ni * 96;
        unsigned short v = 0;
        if (d < HD) v = vtmp[(size_t)(n0 + ni) * C + h * HD + d];
        lt[ni * 104 + d] = v;
    }
    __syncthreads();
#pragma unroll
    for (int i = 0; i < 24; i++) {
        int idx = i * 256 + tid;
        int d = idx >> 6, ni = idx & 63;
        vt[((size_t)h * VD96 + d) * N_TOK + n0 + ni] = lt[ni * 104 + d];
    }
}

// ---------------- flash attention: QBLK=128 (4 qg x 2 kh), KVBLK=128 double-buffered,
//                  global_load_lds DMA staging (linear dest + inverse-swizzled source) ----------------
__launch_bounds__(512, 2)
__global__ void k_attn(const unsigned short* __restrict__ qb,
                       const unsigned short* __restrict__ kb,
                       const unsigned short* __restrict__ vt,
                       unsigned short* __restrict__ ahi,
                       unsigned short* __restrict__ alo) {
    __shared__ __align__(16) unsigned short Kl[2][128 * 128];   // 64KB: [key][16 swizzled slots]
    __shared__ __align__(16) unsigned short Vl[2][96 * 128];    // 48KB: [d][16 swizzled slots]
    int tid = threadIdx.x, lane = tid & 63, wid = tid >> 6;
    int wq = wid & 3;            // q-group of 32 rows
    int kh = wid >> 2;           // key half [0,2): 64 keys each
    int hi = lane >> 5, lq = lane & 31;
    int bid = blockIdx.x;
    int head = bid & 7;          // head == XCD -> K/V L2-resident
    int q0 = (bid >> 3) * 128;
    const float SC2 = 0.12309149097933274f * 1.4426950408889634f;  // 66^-0.5 * log2(e)

    bf16x8 aq[6];
    {
        const unsigned short* qrow = qb + ((size_t)head * N_TOK + q0 + wq * 32 + lq) * HDP + hi * 8;
#pragma unroll
        for (int t = 0; t < 6; t++) aq[t] = *(const bf16x8*)&qrow[t * 16];
    }
    f32x16 o0 = {}, o1 = {}, o2 = {};
    float m_r = -3e38f, l_r = 0.f;

    const unsigned short* kg = kb + (size_t)head * N_TOK * HDP;
    const unsigned short* vg = vt + (size_t)head * VD96 * N_TOK;

    // DMA staging: K = 2048 chunks (128 rows x 16 slots; slots 12-15 are pad, written with
    // harmless in-bounds garbage, never read), V = 1536 chunks (96 rows x 16 slots, all valid).
    // LDS dest is linear in chunk id; source pre-applies the XOR-involution swizzle (rule #21).
    const unsigned short* kSrc[4];
    const unsigned short* vSrc[3];
    int kDst[4], vDst[3];
#pragma unroll
    for (int j = 0; j < 4; j++) {
        int c = (wid * 4 + j) * 64 + lane;
        int row = c >> 4, s = c & 15;
        kSrc[j] = kg + (size_t)row * HDP + ((s ^ (row & 15)) << 3);
        kDst[j] = (wid * 4 + j) * 512;   // shorts: 64 lanes x 8 shorts
    }
#pragma unroll
    for (int j = 0; j < 3; j++) {
        int c = (wid * 3 + j) * 64 + lane;
        int row = c >> 4, s = c & 15;
        vSrc[j] = vg + (size_t)row * N_TOK + ((s ^ (row & 15)) << 3);
        vDst[j] = (wid * 3 + j) * 512;
    }
    // prologue: DMA tile 0 into buffer 0
#pragma unroll
    for (int j = 0; j < 4; j++) gload16(kSrc[j], &Kl[0][kDst[j]]);
#pragma unroll
    for (int j = 0; j < 3; j++) gload16(vSrc[j], &Vl[0][vDst[j]]);
    asm volatile("s_waitcnt vmcnt(0)" ::: "memory");
    __syncthreads();

    int r0 = kh * 64 + lq, r1 = r0 + 32;
    int rv0 = lq, rv1 = 32 + lq, rv2 = 64 + lq;

    for (int kt = 0; kt < 32; kt++) {
        int cur = kt & 1;
        // issue next tile's DMA into the other buffer; lands during this tile's compute
        if (kt < 31) {
            int nxt = cur ^ 1;
            size_t advK = (size_t)(kt + 1) * 128 * HDP;
            size_t advV = (size_t)(kt + 1) * 128;
#pragma unroll
            for (int j = 0; j < 4; j++) gload16(kSrc[j] + advK, &Kl[nxt][kDst[j]]);
#pragma unroll
            for (int j = 0; j < 3; j++) gload16(vSrc[j] + advV, &Vl[nxt][vDst[j]]);
        }
        const unsigned short* Kc = &Kl[cur][0];
        const unsigned short* Vc = &Vl[cur][0];

        // S = K Q^T over this wave's 64-key half
        f32x16 s0 = {}, s1 = {};
        __builtin_amdgcn_s_setprio(1);
#pragma unroll
        for (int t = 0; t < 6; t++) {
            bf16x8 ka0 = *(const bf16x8*)&Kc[r0 * 128 + (((2 * t + hi) ^ (r0 & 15)) << 3)];
            bf16x8 ka1 = *(const bf16x8*)&Kc[r1 * 128 + (((2 * t + hi) ^ (r1 & 15)) << 3)];
            s0 = __builtin_amdgcn_mfma_f32_32x32x16_bf16(ka0, aq[t], s0, 0, 0, 0);
            s1 = __builtin_amdgcn_mfma_f32_32x32x16_bf16(ka1, aq[t], s1, 0, 0, 0);
        }
        __builtin_amdgcn_s_setprio(0);

        // hoist V reads for t2=0,1 -- latency hides under the softmax VALU below
        bf16x8 hv[6];
#pragma unroll
        for (int t2 = 0; t2 < 2; t2++) {
            int ch = kh * 8 + 2 * t2 + hi;
            hv[t2 * 3 + 0] = *(const bf16x8*)&Vc[rv0 * 128 + ((ch ^ (rv0 & 15)) << 3)];
            hv[t2 * 3 + 1] = *(const bf16x8*)&Vc[rv1 * 128 + ((ch ^ (rv1 & 15)) << 3)];
            hv[t2 * 3 + 2] = *(const bf16x8*)&Vc[rv2 * 128 + ((ch ^ (rv2 & 15)) << 3)];
        }

        // online softmax with defer-rescale (T13); 4-chain reductions for ILP
        float ma = fmaxf(s0[0], s1[0]), mb = fmaxf(s0[1], s1[1]);
        float mc = fmaxf(s0[2], s1[2]), md = fmaxf(s0[3], s1[3]);
#pragma unroll
        for (int r = 4; r < 16; r += 4) {
            ma = fmaxf(ma, fmaxf(s0[r + 0], s1[r + 0]));
            mb = fmaxf(mb, fmaxf(s0[r + 1], s1[r + 1]));
            mc = fmaxf(mc, fmaxf(s0[r + 2], s1[r + 2]));
            md = fmaxf(md, fmaxf(s0[r + 3], s1[r + 3]));
        }
        float mx = fmaxf(fmaxf(ma, mb), fmaxf(mc, md));
        mx = fmaxf(mx, __shfl_xor(mx, 32, 64));
        if (!__all((mx - m_r) * SC2 <= 8.f)) {
            float mnew = fmaxf(m_r, mx);
            float fct = __builtin_amdgcn_exp2f((m_r - mnew) * SC2);
            m_r = mnew;
            l_r *= fct;
#pragma unroll
            for (int r = 0; r < 16; r++) { o0[r] *= fct; o1[r] *= fct; o2[r] *= fct; }
        }
        float nb = m_r * SC2;
        float la = 0.f, lb = 0.f, lc = 0.f, ld = 0.f;
#pragma unroll
        for (int r = 0; r < 16; r += 4) {
            s0[r + 0] = __builtin_amdgcn_exp2f(__builtin_fmaf(s0[r + 0], SC2, -nb)); la += s0[r + 0];
            s0[r + 1] = __builtin_amdgcn_exp2f(__builtin_fmaf(s0[r + 1], SC2, -nb)); lb += s0[r + 1];
            s0[r + 2] = __builtin_amdgcn_exp2f(__builtin_fmaf(s0[r + 2], SC2, -nb)); lc += s0[r + 2];
            s0[r + 3] = __builtin_amdgcn_exp2f(__builtin_fmaf(s0[r + 3], SC2, -nb)); ld += s0[r + 3];
        }
#pragma unroll
        for (int r = 0; r < 16; r += 4) {
            s1[r + 0] = __builtin_amdgcn_exp2f(__builtin_fmaf(s1[r + 0], SC2, -nb)); la += s1[r + 0];
            s1[r + 1] = __builtin_amdgcn_exp2f(__builtin_fmaf(s1[r + 1], SC2, -nb)); lb += s1[r + 1];
            s1[r + 2] = __builtin_amdgcn_exp2f(__builtin_fmaf(s1[r + 2], SC2, -nb)); lc += s1[r + 2];
            s1[r + 3] = __builtin_amdgcn_exp2f(__builtin_fmaf(s1[r + 3], SC2, -nb)); ld += s1[r + 3];
        }
        float lsum = (la + lb) + (lc + ld);
        lsum += __shfl_xor(lsum, 32, 64);
        l_r += lsum;

        // pack P into PV B-fragments: 16 cvt_pk + 8 permlane32_swap (T12)
        unsigned u0[2][4], u1[2][4];
#pragma unroll
        for (int a = 0; a < 4; a++) {
            u0[0][a] = cvtpk2(s0[4 * a + 0], s0[4 * a + 1]);
            u1[0][a] = cvtpk2(s0[4 * a + 2], s0[4 * a + 3]);
            u0[1][a] = cvtpk2(s1[4 * a + 0], s1[4 * a + 1]);
            u1[1][a] = cvtpk2(s1[4 * a + 2], s1[4 * a + 3]);
        }
#pragma unroll
        for (int kb2 = 0; kb2 < 2; kb2++)
#pragma unroll
            for (int a0 = 0; a0 < 4; a0 += 2) {
                plswap(u0[kb2][a0], u0[kb2][a0 + 1]);
                plswap(u1[kb2][a0], u1[kb2][a0 + 1]);
            }

        // O^T += V^T P over this wave's key half
        __builtin_amdgcn_s_setprio(1);
#pragma unroll
        for (int t2 = 0; t2 < 4; t2++) {
            int kb2 = t2 >> 1, a0 = (t2 & 1) * 2;
            union { unsigned u[4]; bf16x8 v; } pf;
            pf.u[0] = u0[kb2][a0];     pf.u[1] = u1[kb2][a0];
            pf.u[2] = u0[kb2][a0 + 1]; pf.u[3] = u1[kb2][a0 + 1];
            bf16x8 va0, va1, va2;
            if (t2 < 2) {
                va0 = hv[t2 * 3 + 0]; va1 = hv[t2 * 3 + 1]; va2 = hv[t2 * 3 + 2];
            } else {
                int ch = kh * 8 + 2 * t2 + hi;
                va0 = *(const bf16x8*)&Vc[rv0 * 128 + ((ch ^ (rv0 & 15)) << 3)];
                va1 = *(const bf16x8*)&Vc[rv1 * 128 + ((ch ^ (rv1 & 15)) << 3)];
                va2 = *(const bf16x8*)&Vc[rv2 * 128 + ((ch ^ (rv2 & 15)) << 3)];
            }
            o0 = __builtin_amdgcn_mfma_f32_32x32x16_bf16(va0, pf.v, o0, 0, 0, 0);
            o1 = __builtin_amdgcn_mfma_f32_32x32x16_bf16(va1, pf.v, o1, 0, 0, 0);
            o2 = __builtin_amdgcn_mfma_f32_32x32x16_bf16(va2, pf.v, o2, 0, 0, 0);
        }
        __builtin_amdgcn_s_setprio(0);

        // drain own DMA (issued a full tile ago -> already landed), then barrier
        asm volatile("s_waitcnt vmcnt(0)" ::: "memory");
        __syncthreads();
    }

    // ---- combine key-half partials (kh=1 -> LDS, kh=0 merges & stores) ----
    float* xc = (float*)&Kl[0][0];
    float* rg = xc + (size_t)((wq * 64 + lane) * 52);
    if (kh == 1) {
#pragma unroll
        for (int r = 0; r < 16; r++) { rg[r] = o0[r]; rg[16 + r] = o1[r]; rg[32 + r] = o2[r]; }
        rg[48] = m_r; rg[49] = l_r;
    }
    __syncthreads();
    if (kh == 0) {
        float m1 = rg[48], l1 = rg[49];
        float m12 = fmaxf(m_r, m1);
        float f0 = __builtin_amdgcn_exp2f((m_r - m12) * SC2);
        float f1 = __builtin_amdgcn_exp2f((m1 - m12) * SC2);
        float inv = 1.f / (l_r * f0 + l1 * f1);
        int token = q0 + wq * 32 + lq;
#pragma unroll
        for (int db = 0; db < 3; db++) {
#pragma unroll
            for (int r = 0; r < 16; r++) {
                int d = db * 32 + (r & 3) + 8 * (r >> 2) + 4 * hi;
                if (d < HD) {
                    float own = (db == 0) ? o0[r] : (db == 1) ? o1[r] : o2[r];
                    float val = (own * f0 + rg[db * 16 + r] * f1) * inv;
                    unsigned short hb = f2bf(val);
                    float lo = val - bf2f(hb);
                    size_t a = (size_t)token * KP + head * HD + d;
                    ahi[a] = hb; alo[a] = f2bf(lo);
                }
            }
        }
    }
}

// ---------------- proj GEMM (split-precision, BN=64, double-buffered) ----------------
__launch_bounds__(256)
__global__ void k_gemm_proj(const unsigned short* __restrict__ Ahi_, const unsigned short* __restrict__ Alo_,
                            const unsigned short* __restrict__ Whi_, const unsigned short* __restrict__ Wlo_,
                            const float* __restrict__ bias, float* __restrict__ out) {
    constexpr int LDA = 40;
    __shared__ unsigned short Ah[2][128 * LDA], Aw[2][128 * LDA];
    __shared__ unsigned short Bh[2][64 * LDA],  Bw[2][64 * LDA];
    int tid = threadIdx.x, lane = tid & 63, wid = tid >> 6;
    int m0 = blockIdx.x * 128, n0 = blockIdx.y * 64;
    int wm = wid * 32;
    int arow0 = tid >> 2, arow1 = (256 + tid) >> 2, akc = (tid & 3) * 8;
    bool bok = (n0 + arow0) < KP;
    f32x4 acc[2][4] = {};
    bf16x8 rah0, rah1, ral0, ral1, rbh, rbl;
    const bf16x8 zero8 = {};

    rah0 = *(const bf16x8*)&Ahi_[(size_t)(m0 + arow0) * KP + akc];
    rah1 = *(const bf16x8*)&Ahi_[(size_t)(m0 + arow1) * KP + akc];
    ral0 = *(const bf16x8*)&Alo_[(size_t)(m0 + arow0) * KP + akc];
    ral1 = *(const bf16x8*)&Alo_[(size_t)(m0 + arow1) * KP + akc];
    rbh = bok ? *(const bf16x8*)&Whi_[(size_t)(n0 + arow0) * KP + akc] : zero8;
    rbl = bok ? *(const bf16x8*)&Wlo_[(size_t)(n0 + arow0) * KP + akc] : zero8;
    *(bf16x8*)&Ah[0][arow0 * LDA + akc] = rah0;
    *(bf16x8*)&Ah[0][arow1 * LDA + akc] = rah1;
    *(bf16x8*)&Aw[0][arow0 * LDA + akc] = ral0;
    *(bf16x8*)&Aw[0][arow1 * LDA + akc] = ral1;
    *(bf16x8*)&Bh[0][arow0 * LDA + akc] = rbh;
    *(bf16x8*)&Bw[0][arow0 * LDA + akc] = rbl;
    __syncthreads();

    int kk = (lane >> 4) * 8, cc = lane & 15;
    for (int kt = 0; kt < 17; kt++) {
        int cur = kt & 1;
        if (kt < 16) {
            int k0 = (kt + 1) * 32;
            rah0 = *(const bf16x8*)&Ahi_[(size_t)(m0 + arow0) * KP + k0 + akc];
            rah1 = *(const bf16x8*)&Ahi_[(size_t)(m0 + arow1) * KP + k0 + akc];
            ral0 = *(const bf16x8*)&Alo_[(size_t)(m0 + arow0) * KP + k0 + akc];
            ral1 = *(const bf16x8*)&Alo_[(size_t)(m0 + arow1) * KP + k0 + akc];
            rbh = bok ? *(const bf16x8*)&Whi_[(size_t)(n0 + arow0) * KP + k0 + akc] : zero8;
            rbl = bok ? *(const bf16x8*)&Wlo_[(size_t)(n0 + arow0) * KP + k0 + akc] : zero8;
        }
        bf16x8 ah[2], al[2], bh[4], bl[4];
#pragma unroll
        for (int mi = 0; mi < 2; mi++) {
            ah[mi] = *(const bf16x8*)&Ah[cur][(wm + mi * 16 + cc) * LDA + kk];
            al[mi] = *(const bf16x8*)&Aw[cur][(wm + mi * 16 + cc) * LDA + kk];
        }
#pragma unroll
        for (int ni = 0; ni < 4; ni++) {
            bh[ni] = *(const bf16x8*)&Bh[cur][(ni * 16 + cc) * LDA + kk];
            bl[ni] = *(const bf16x8*)&Bw[cur][(ni * 16 + cc) * LDA + kk];
        }
#pragma unroll
        for (int mi = 0; mi < 2; mi++)
#pragma unroll
            for (int ni = 0; ni < 4; ni++) {
                acc[mi][ni] = __builtin_amdgcn_mfma_f32_16x16x32_bf16(ah[mi], bh[ni], acc[mi][ni], 0, 0, 0);
                acc[mi][ni] = __builtin_amdgcn_mfma_f32_16x16x32_bf16(ah[mi], bl[ni], acc[mi][ni], 0, 0, 0);
                acc[mi][ni] = __builtin_amdgcn_mfma_f32_16x16x32_bf16(al[mi], bh[ni], acc[mi][ni], 0, 0, 0);
            }
        if (kt < 16) {
            int nxt = cur ^ 1;
            *(bf16x8*)&Ah[nxt][arow0 * LDA + akc] = rah0;
            *(bf16x8*)&Ah[nxt][arow1 * LDA + akc] = rah1;
            *(bf16x8*)&Aw[nxt][arow0 * LDA + akc] = ral0;
            *(bf16x8*)&Aw[nxt][arow1 * LDA + akc] = ral1;
            *(bf16x8*)&Bh[nxt][arow0 * LDA + akc] = rbh;
            *(bf16x8*)&Bw[nxt][arow0 * LDA + akc] = rbl;
        }
        __syncthreads();
    }
#pragma unroll
    for (int mi = 0; mi < 2; mi++)
#pragma unroll
        for (int ni = 0; ni < 4; ni++)
#pragma unroll
            for (int r = 0; r < 4; r++) {
                int row = m0 + wm + mi * 16 + (lane >> 4) * 4 + r;
                int col = n0 + ni * 16 + cc;
                if (col < C) out[(size_t)row * C + col] = acc[mi][ni][r] + bias[col];
            }
}

extern "C" void kernel_launch(void* const* d_in, const int* in_sizes, int n_in,
                              void* d_out, int out_size, void* d_ws, size_t ws_size,
                              hipStream_t stream) {
    const float* x      = (const float*)d_in[0];
    const float* w_qkv  = (const float*)d_in[1];
    const float* b_qkv  = (const float*)d_in[2];
    const float* w_proj = (const float*)d_in[3];
    const float* b_proj = (const float*)d_in[4];
    float* out = (float*)d_out;
    char* ws = (char*)d_ws;

    const size_t o_xb    = 0;
    const size_t o_wqkvb = o_xb    + 4456448;
    const size_t o_whi   = o_wqkvb + 1775616;
    const size_t o_wlo   = o_whi   + 591872;
    const size_t o_vtmp  = o_wlo   + 591872;
    const size_t o_qbf   = o_vtmp  + 4456448;
    const size_t o_kbf   = o_qbf   + 6291456;
    const size_t o_vt    = o_kbf   + 6291456;
    const size_t need    = o_vt + 6291456;
    if (ws_size < need) return;

    unsigned short* xb    = (unsigned short*)(ws + o_xb);
    unsigned short* wqkvb = (unsigned short*)(ws + o_wqkvb);
    unsigned short* whi   = (unsigned short*)(ws + o_whi);
    unsigned short* wlo   = (unsigned short*)(ws + o_wlo);
    unsigned short* vtmp  = (unsigned short*)(ws + o_vtmp);
    unsigned short* qbf   = (unsigned short*)(ws + o_qbf);
    unsigned short* kbf   = (unsigned short*)(ws + o_kbf);
    unsigned short* vt    = (unsigned short*)(ws + o_vt);
    unsigned short* ahi   = xb;
    unsigned short* alo   = vtmp;

    k_prep_all  <<<2048, 256, 0, stream>>>(x, w_qkv, w_proj, xb, wqkvb, whi, wlo, qbf, kbf);
    k_gemm_qkv  <<<dim3(N_TOK / 128, NQKVP / 96), 256, 0, stream>>>(xb, wqkvb, b_qkv, qbf, kbf, vtmp);
    k_reshape_v <<<dim3(N_TOK / 64, NH), 256, 0, stream>>>(vtmp, vt);
    k_attn      <<<dim3(256), 512, 0, stream>>>(qbf, kbf, vt, ahi, alo);
    k_gemm_proj <<<dim3(N_TOK / 128, 9), 256, 0, stream>>>(ahi, alo, whi, wlo, b_proj, out);
}

// Round 12
// 130.349 us; speedup vs baseline: 1.0717x; 1.0717x over previous
//
#include <hip/hip_runtime.h>

typedef __attribute__((ext_vector_type(8))) short bf16x8;
typedef __attribute__((ext_vector_type(4))) float f32x4;
typedef __attribute__((ext_vector_type(16))) float f32x16;

#define DEV __device__ __forceinline__

static constexpr int N_TOK = 4096;
static constexpr int C     = 528;
static constexpr int NH    = 8;
static constexpr int HD    = 66;
static constexpr int HDP   = 96;    // q/k head-dim padded
static constexpr int VD96  = 96;    // v head-dim padded
static constexpr int KP    = 544;   // GEMM K padded (17*32)
static constexpr int NQKV  = 1584;
static constexpr int NQKVP = 1632;  // 17*96

DEV unsigned short f2bf(float f) {
    unsigned int u = __float_as_uint(f);
    u = (u + 0x7fffu + ((u >> 16) & 1u)) >> 16;
    return (unsigned short)u;
}
DEV float bf2f(unsigned short h) { return __uint_as_float(((unsigned int)h) << 16); }
DEV unsigned cvtpk2(float a, float b) {
    unsigned r;
    asm("v_cvt_pk_bf16_f32 %0, %1, %2" : "=v"(r) : "v"(a), "v"(b));
    return r;
}
DEV void plswap(unsigned &a, unsigned &b) {
    asm volatile("v_permlane32_swap_b32 %0, %1" : "+v"(a), "+v"(b));
}

// ---------------- fused prep: xb, wqkvb, whi/wlo, qb/kb pad-zeroing ----------------
__global__ void k_prep_all(const float* __restrict__ x, const float* __restrict__ w_qkv,
                           const float* __restrict__ w_proj,
                           unsigned short* __restrict__ xb, unsigned short* __restrict__ wqkvb,
                           unsigned short* __restrict__ whi, unsigned short* __restrict__ wlo,
                           unsigned short* __restrict__ qb, unsigned short* __restrict__ kbuf) {
    const int T0 = N_TOK * KP;
    const int T1 = T0 + NQKVP * KP;
    const int T2 = T1 + KP * KP;
    const int T3 = T2 + NH * N_TOK * (HDP - HD);
    for (int idx = blockIdx.x * 256 + threadIdx.x; idx < T3; idx += gridDim.x * 256) {
        if (idx < T0) {
            int n = idx / KP, k = idx - n * KP;
            xb[idx] = (k < C) ? f2bf(x[n * C + k]) : (unsigned short)0;
        } else if (idx < T1) {
            int j = idx - T0;
            int n = j / KP, k = j - n * KP;
            wqkvb[j] = (n < NQKV && k < C) ? f2bf(w_qkv[n * C + k]) : (unsigned short)0;
        } else if (idx < T2) {
            int j = idx - T1;
            int n = j / KP, k = j - n * KP;
            unsigned short hi = 0, lo = 0;
            if (n < C && k < C) {
                float v = w_proj[n * C + k];
                hi = f2bf(v);
                lo = f2bf(v - bf2f(hi));
            }
            whi[j] = hi; wlo[j] = lo;
        } else {
            int j = idx - T2;
            int n = j / 30, p = j - 30 * n;
            size_t a = (size_t)n * HDP + HD + p;
            qb[a] = 0; kbuf[a] = 0;
        }
    }
}

// ---------------- QKV GEMM (double-buffered); epilogue scatters q/k, writes v slab ----------------
__launch_bounds__(256)
__global__ void k_gemm_qkv(const unsigned short* __restrict__ A,
                           const unsigned short* __restrict__ B,
                           const float* __restrict__ bias,
                           unsigned short* __restrict__ qb, unsigned short* __restrict__ kbuf,
                           unsigned short* __restrict__ vtmp) {
    constexpr int LDA = 40;
    __shared__ unsigned short Al[2][128 * LDA];
    __shared__ unsigned short Bl[2][96 * LDA];
    int tid = threadIdx.x, lane = tid & 63, wid = tid >> 6;
    int m0 = blockIdx.x * 128, n0 = blockIdx.y * 96;
    int wm = (wid >> 1) * 64, wn = (wid & 1) * 48;
    int arow0 = tid >> 2, arow1 = (256 + tid) >> 2, akc = (tid & 3) * 8;
    bool bhave = tid < 128;
    int brow1 = (256 + tid) >> 2;
    f32x4 acc[4][3] = {};
    bf16x8 ra0, ra1, rb0, rb1;

    ra0 = *(const bf16x8*)&A[(size_t)(m0 + arow0) * KP + akc];
    ra1 = *(const bf16x8*)&A[(size_t)(m0 + arow1) * KP + akc];
    rb0 = *(const bf16x8*)&B[(size_t)(n0 + arow0) * KP + akc];
    if (bhave) rb1 = *(const bf16x8*)&B[(size_t)(n0 + brow1) * KP + akc];
    *(bf16x8*)&Al[0][arow0 * LDA + akc] = ra0;
    *(bf16x8*)&Al[0][arow1 * LDA + akc] = ra1;
    *(bf16x8*)&Bl[0][arow0 * LDA + akc] = rb0;
    if (bhave) *(bf16x8*)&Bl[0][brow1 * LDA + akc] = rb1;
    __syncthreads();

    int kk = (lane >> 4) * 8, cc = lane & 15;
    for (int kt = 0; kt < 17; kt++) {
        int cur = kt & 1;
        if (kt < 16) {
            int k0 = (kt + 1) * 32;
            ra0 = *(const bf16x8*)&A[(size_t)(m0 + arow0) * KP + k0 + akc];
            ra1 = *(const bf16x8*)&A[(size_t)(m0 + arow1) * KP + k0 + akc];
            rb0 = *(const bf16x8*)&B[(size_t)(n0 + arow0) * KP + k0 + akc];
            if (bhave) rb1 = *(const bf16x8*)&B[(size_t)(n0 + brow1) * KP + k0 + akc];
        }
        bf16x8 af[4], bfr[3];
#pragma unroll
        for (int mi = 0; mi < 4; mi++) af[mi] = *(const bf16x8*)&Al[cur][(wm + mi * 16 + cc) * LDA + kk];
#pragma unroll
        for (int ni = 0; ni < 3; ni++) bfr[ni] = *(const bf16x8*)&Bl[cur][(wn + ni * 16 + cc) * LDA + kk];
#pragma unroll
        for (int mi = 0; mi < 4; mi++)
#pragma unroll
            for (int ni = 0; ni < 3; ni++)
                acc[mi][ni] = __builtin_amdgcn_mfma_f32_16x16x32_bf16(af[mi], bfr[ni], acc[mi][ni], 0, 0, 0);
        if (kt < 16) {
            int nxt = cur ^ 1;
            *(bf16x8*)&Al[nxt][arow0 * LDA + akc] = ra0;
            *(bf16x8*)&Al[nxt][arow1 * LDA + akc] = ra1;
            *(bf16x8*)&Bl[nxt][arow0 * LDA + akc] = rb0;
            if (bhave) *(bf16x8*)&Bl[nxt][brow1 * LDA + akc] = rb1;
        }
        __syncthreads();
    }
#pragma unroll
    for (int mi = 0; mi < 4; mi++)
#pragma unroll
        for (int ni = 0; ni < 3; ni++)
#pragma unroll
            for (int r = 0; r < 4; r++) {
                int row = m0 + wm + mi * 16 + (lane >> 4) * 4 + r;
                int col = n0 + wn + ni * 16 + cc;
                float v = acc[mi][ni][r] + (col < NQKV ? bias[col] : 0.f);
                unsigned short b = f2bf(v);
                if (col < 2 * C) {
                    int d5 = (col >= C) ? col - C : col;
                    unsigned h = (unsigned)d5 / 66u;
                    int dd = d5 - 66 * (int)h;
                    size_t a = ((size_t)h * N_TOK + row) * HDP + dd;
                    if (col >= C) kbuf[a] = b; else qb[a] = b;
                } else if (col < NQKV) {
                    vtmp[(size_t)row * C + (col - 2 * C)] = b;
                }
            }
}

// ---------------- v transpose: vtmp[4096][528] -> vt[8][96][4096] ----------------
__global__ void k_reshape_v(const unsigned short* __restrict__ vtmp, unsigned short* __restrict__ vt) {
    __shared__ unsigned short lt[64 * 104];
    int h = blockIdx.y, n0 = blockIdx.x * 64, tid = threadIdx.x;
#pragma unroll
    for (int i = 0; i < 24; i++) {
        int idx = i * 256 + tid;
        int ni = idx / 96, d = idx - ni * 96;
        unsigned short v = 0;
        if (d < HD) v = vtmp[(size_t)(n0 + ni) * C + h * HD + d];
        lt[ni * 104 + d] = v;
    }
    __syncthreads();
#pragma unroll
    for (int i = 0; i < 24; i++) {
        int idx = i * 256 + tid;
        int d = idx >> 6, ni = idx & 63;
        vt[((size_t)h * VD96 + d) * N_TOK + n0 + ni] = lt[ni * 104 + d];
    }
}

// ---------------- flash attention: dual-Q-block waves (2 MFMA per LDS A-read) ----------------
// 8 waves = 2 q-supergroups (64 rows) x 4 key-quarters (32 keys); QBLK=128, KVBLK=128 dbuf.
__launch_bounds__(512, 1)
__global__ void k_attn(const unsigned short* __restrict__ qb,
                       const unsigned short* __restrict__ kb,
                       const unsigned short* __restrict__ vt,
                       unsigned short* __restrict__ ahi,
                       unsigned short* __restrict__ alo) {
    __shared__ __align__(16) unsigned short Kl[2][128 * 128];   // 64KB
    __shared__ __align__(16) unsigned short Vl[2][96 * 128];    // 48KB
    int tid = threadIdx.x, lane = tid & 63, wid = tid >> 6;
    int qsg = wid & 1;           // q-supergroup of 64 rows
    int kh  = wid >> 1;          // key quarter [0,4): 32 keys each
    int hi = lane >> 5, lq = lane & 31;
    int bid = blockIdx.x;
    int head = bid & 7;          // head == XCD -> K/V L2-resident
    int q0 = (bid >> 3) * 128;
    const float SC2 = 0.12309149097933274f * 1.4426950408889634f;  // 66^-0.5 * log2(e)

    // two Q-blocks per wave, both in registers
    bf16x8 aq0[6], aq1[6];
    {
        const unsigned short* qr0 = qb + ((size_t)head * N_TOK + q0 + qsg * 64 + lq) * HDP + hi * 8;
        const unsigned short* qr1 = qr0 + 32 * HDP;
#pragma unroll
        for (int t = 0; t < 6; t++) { aq0[t] = *(const bf16x8*)&qr0[t * 16]; aq1[t] = *(const bf16x8*)&qr1[t * 16]; }
    }
    f32x16 o0a = {}, o0b = {}, o0c = {};   // qg0: d-blocks 0..2
    f32x16 o1a = {}, o1b = {}, o1c = {};   // qg1
    float m0r = -3e38f, l0r = 0.f, m1r = -3e38f, l1r = 0.f;

    const unsigned short* kg = kb + (size_t)head * N_TOK * HDP;
    const unsigned short* vg = vt + (size_t)head * VD96 * N_TOK;

    // staging: K 128x12=1536 chunks + V 96x16=1536 chunks = 3072 / 512 threads = 3K + 3V each
    const unsigned short* gpK[3];
    const unsigned short* gpV[3];
    int laK[3], laV[3];
#pragma unroll
    for (int j = 0; j < 3; j++) {
        int c = j * 512 + tid;
        int row = c / 12, ch = c - row * 12;
        gpK[j] = kg + (size_t)row * HDP + ch * 8;
        laK[j] = row * 128 + ((ch ^ (row & 15)) << 3);
        int row2 = c >> 4, ch2 = c & 15;
        gpV[j] = vg + (size_t)row2 * N_TOK + ch2 * 8;
        laV[j] = row2 * 128 + ((ch2 ^ (row2 & 15)) << 3);
    }
#pragma unroll
    for (int j = 0; j < 3; j++) {
        *(bf16x8*)&Kl[0][laK[j]] = *(const bf16x8*)gpK[j];
        *(bf16x8*)&Vl[0][laV[j]] = *(const bf16x8*)gpV[j];
    }
    __syncthreads();

    int rk = kh * 32 + lq;                       // this wave's key row
    int rv0 = lq, rv1 = 32 + lq, rv2 = 64 + lq;  // V d-rows

    for (int kt = 0; kt < 32; kt++) {
        int cur = kt & 1;
        bf16x8 gk[3], gv[3];
        if (kt < 31) {
            size_t n1 = (size_t)(kt + 1) * 128;
#pragma unroll
            for (int j = 0; j < 3; j++) {
                gk[j] = *(const bf16x8*)(gpK[j] + n1 * HDP);
                gv[j] = *(const bf16x8*)(gpV[j] + n1);
            }
        }
        const unsigned short* Kc = &Kl[cur][0];
        const unsigned short* Vc = &Vl[cur][0];

        // S = K Q^T: one K-read feeds BOTH q-blocks
        f32x16 s0 = {}, s1 = {};
        __builtin_amdgcn_s_setprio(1);
#pragma unroll
        for (int t = 0; t < 6; t++) {
            bf16x8 ka = *(const bf16x8*)&Kc[rk * 128 + (((2 * t + hi) ^ (rk & 15)) << 3)];
            s0 = __builtin_amdgcn_mfma_f32_32x32x16_bf16(ka, aq0[t], s0, 0, 0, 0);
            s1 = __builtin_amdgcn_mfma_f32_32x32x16_bf16(ka, aq1[t], s1, 0, 0, 0);
        }
        __builtin_amdgcn_s_setprio(0);

        // online softmax per q-group (independent -> natural ILP)
        {
            float mx = s0[0];
#pragma unroll
            for (int r = 1; r < 16; r++) mx = fmaxf(mx, s0[r]);
            mx = fmaxf(mx, __shfl_xor(mx, 32, 64));
            if (!__all((mx - m0r) * SC2 <= 8.f)) {
                float mnew = fmaxf(m0r, mx);
                float fct = __builtin_amdgcn_exp2f((m0r - mnew) * SC2);
                m0r = mnew; l0r *= fct;
#pragma unroll
                for (int r = 0; r < 16; r++) { o0a[r] *= fct; o0b[r] *= fct; o0c[r] *= fct; }
            }
            float nb = m0r * SC2, lsum = 0.f;
#pragma unroll
            for (int r = 0; r < 16; r++) { s0[r] = __builtin_amdgcn_exp2f(__builtin_fmaf(s0[r], SC2, -nb)); lsum += s0[r]; }
            lsum += __shfl_xor(lsum, 32, 64);
            l0r += lsum;
        }
        {
            float mx = s1[0];
#pragma unroll
            for (int r = 1; r < 16; r++) mx = fmaxf(mx, s1[r]);
            mx = fmaxf(mx, __shfl_xor(mx, 32, 64));
            if (!__all((mx - m1r) * SC2 <= 8.f)) {
                float mnew = fmaxf(m1r, mx);
                float fct = __builtin_amdgcn_exp2f((m1r - mnew) * SC2);
                m1r = mnew; l1r *= fct;
#pragma unroll
                for (int r = 0; r < 16; r++) { o1a[r] *= fct; o1b[r] *= fct; o1c[r] *= fct; }
            }
            float nb = m1r * SC2, lsum = 0.f;
#pragma unroll
            for (int r = 0; r < 16; r++) { s1[r] = __builtin_amdgcn_exp2f(__builtin_fmaf(s1[r], SC2, -nb)); lsum += s1[r]; }
            lsum += __shfl_xor(lsum, 32, 64);
            l1r += lsum;
        }

        // pack P (both q-groups): 8 cvt + 4 swaps each
        unsigned u00[4], u01[4], u10[4], u11[4];
#pragma unroll
        for (int a = 0; a < 4; a++) {
            u00[a] = cvtpk2(s0[4 * a + 0], s0[4 * a + 1]);
            u01[a] = cvtpk2(s0[4 * a + 2], s0[4 * a + 3]);
            u10[a] = cvtpk2(s1[4 * a + 0], s1[4 * a + 1]);
            u11[a] = cvtpk2(s1[4 * a + 2], s1[4 * a + 3]);
        }
        plswap(u00[0], u00[1]); plswap(u00[2], u00[3]);
        plswap(u01[0], u01[1]); plswap(u01[2], u01[3]);
        plswap(u10[0], u10[1]); plswap(u10[2], u10[3]);
        plswap(u11[0], u11[1]); plswap(u11[2], u11[3]);

        // O^T += V^T P: one V-read feeds BOTH q-blocks
        __builtin_amdgcn_s_setprio(1);
#pragma unroll
        for (int t2 = 0; t2 < 2; t2++) {
            int a0 = t2 * 2;
            union { unsigned u[4]; bf16x8 v; } p0, p1;
            p0.u[0] = u00[a0]; p0.u[1] = u01[a0]; p0.u[2] = u00[a0 + 1]; p0.u[3] = u01[a0 + 1];
            p1.u[0] = u10[a0]; p1.u[1] = u11[a0]; p1.u[2] = u10[a0 + 1]; p1.u[3] = u11[a0 + 1];
            int ch = kh * 4 + 2 * t2 + hi;
            bf16x8 va0 = *(const bf16x8*)&Vc[rv0 * 128 + ((ch ^ (rv0 & 15)) << 3)];
            bf16x8 va1 = *(const bf16x8*)&Vc[rv1 * 128 + ((ch ^ (rv1 & 15)) << 3)];
            bf16x8 va2 = *(const bf16x8*)&Vc[rv2 * 128 + ((ch ^ (rv2 & 15)) << 3)];
            o0a = __builtin_amdgcn_mfma_f32_32x32x16_bf16(va0, p0.v, o0a, 0, 0, 0);
            o1a = __builtin_amdgcn_mfma_f32_32x32x16_bf16(va0, p1.v, o1a, 0, 0, 0);
            o0b = __builtin_amdgcn_mfma_f32_32x32x16_bf16(va1, p0.v, o0b, 0, 0, 0);
            o1b = __builtin_amdgcn_mfma_f32_32x32x16_bf16(va1, p1.v, o1b, 0, 0, 0);
            o0c = __builtin_amdgcn_mfma_f32_32x32x16_bf16(va2, p0.v, o0c, 0, 0, 0);
            o1c = __builtin_amdgcn_mfma_f32_32x32x16_bf16(va2, p1.v, o1c, 0, 0, 0);
        }
        __builtin_amdgcn_s_setprio(0);

        if (kt < 31) {
            int nxt = cur ^ 1;
#pragma unroll
            for (int j = 0; j < 3; j++) {
                *(bf16x8*)&Kl[nxt][laK[j]] = gk[j];
                *(bf16x8*)&Vl[nxt][laV[j]] = gv[j];
            }
        }
        __syncthreads();
    }

    // ---- 2-stage tree combine of 4 key-quarter partials (per q-supergroup) ----
    // layout: ((slot*64 + lane)*2 + qg)*50 floats; slots 0..3 = 102.4KB (< Kl+Vl)
    float* xc = (float*)&Kl[0][0];
    // stage A: kh 2,3 write slot qsg*2+(kh&1); kh 0,1 merge from slot qsg*2+kh
    {
        int slot = qsg * 2 + (kh & 1);
        float* rg0 = xc + (size_t)(((slot * 64 + lane) * 2 + 0) * 50);
        float* rg1 = xc + (size_t)(((slot * 64 + lane) * 2 + 1) * 50);
        if (kh >= 2) {
#pragma unroll
            for (int r = 0; r < 16; r++) {
                rg0[r] = o0a[r]; rg0[16 + r] = o0b[r]; rg0[32 + r] = o0c[r];
                rg1[r] = o1a[r]; rg1[16 + r] = o1b[r]; rg1[32 + r] = o1c[r];
            }
            rg0[48] = m0r; rg0[49] = l0r; rg1[48] = m1r; rg1[49] = l1r;
        }
        __syncthreads();
        if (kh < 2) {
            float mo = rg0[48], lo = rg0[49];
            float mm = fmaxf(m0r, mo);
            float f0 = __builtin_amdgcn_exp2f((m0r - mm) * SC2);
            float f1 = __builtin_amdgcn_exp2f((mo - mm) * SC2);
            l0r = l0r * f0 + lo * f1; m0r = mm;
#pragma unroll
            for (int r = 0; r < 16; r++) {
                o0a[r] = o0a[r] * f0 + rg0[r] * f1;
                o0b[r] = o0b[r] * f0 + rg0[16 + r] * f1;
                o0c[r] = o0c[r] * f0 + rg0[32 + r] * f1;
            }
            mo = rg1[48]; lo = rg1[49];
            mm = fmaxf(m1r, mo);
            f0 = __builtin_amdgcn_exp2f((m1r - mm) * SC2);
            f1 = __builtin_amdgcn_exp2f((mo - mm) * SC2);
            l1r = l1r * f0 + lo * f1; m1r = mm;
#pragma unroll
            for (int r = 0; r < 16; r++) {
                o1a[r] = o1a[r] * f0 + rg1[r] * f1;
                o1b[r] = o1b[r] * f0 + rg1[16 + r] * f1;
                o1c[r] = o1c[r] * f0 + rg1[32 + r] * f1;
            }
        }
        __syncthreads();
    }
    // stage B: kh=1 writes slot qsg; kh=0 merges, normalizes, stores
    {
        float* rg0 = xc + (size_t)(((qsg * 64 + lane) * 2 + 0) * 50);
        float* rg1 = xc + (size_t)(((qsg * 64 + lane) * 2 + 1) * 50);
        if (kh == 1) {
#pragma unroll
            for (int r = 0; r < 16; r++) {
                rg0[r] = o0a[r]; rg0[16 + r] = o0b[r]; rg0[32 + r] = o0c[r];
                rg1[r] = o1a[r]; rg1[16 + r] = o1b[r]; rg1[32 + r] = o1c[r];
            }
            rg0[48] = m0r; rg0[49] = l0r; rg1[48] = m1r; rg1[49] = l1r;
        }
        __syncthreads();
        if (kh == 0) {
#pragma unroll
            for (int qg = 0; qg < 2; qg++) {
                float* rg = qg ? rg1 : rg0;
                float mr = qg ? m1r : m0r;
                float lr = qg ? l1r : l0r;
                float mo = rg[48], lo = rg[49];
                float mm = fmaxf(mr, mo);
                float f0 = __builtin_amdgcn_exp2f((mr - mm) * SC2);
                float f1 = __builtin_amdgcn_exp2f((mo - mm) * SC2);
                float inv = 1.f / (lr * f0 + lo * f1);
                int token = q0 + qsg * 64 + qg * 32 + lq;
#pragma unroll
                for (int db = 0; db < 3; db++) {
#pragma unroll
                    for (int r = 0; r < 16; r++) {
                        int d = db * 32 + (r & 3) + 8 * (r >> 2) + 4 * hi;
                        if (d < HD) {
                            float own;
                            if (qg == 0) own = (db == 0) ? o0a[r] : (db == 1) ? o0b[r] : o0c[r];
                            else         own = (db == 0) ? o1a[r] : (db == 1) ? o1b[r] : o1c[r];
                            float val = (own * f0 + rg[db * 16 + r] * f1) * inv;
                            unsigned short hb = f2bf(val);
                            float lov = val - bf2f(hb);
                            size_t a = (size_t)token * KP + head * HD + d;
                            ahi[a] = hb; alo[a] = f2bf(lov);
                        }
                    }
                }
            }
        }
    }
}

// ---------------- proj GEMM (split-precision, BN=64, double-buffered) ----------------
__launch_bounds__(256)
__global__ void k_gemm_proj(const unsigned short* __restrict__ Ahi_, const unsigned short* __restrict__ Alo_,
                            const unsigned short* __restrict__ Whi_, const unsigned short* __restrict__ Wlo_,
                            const float* __restrict__ bias, float* __restrict__ out) {
    constexpr int LDA = 40;
    __shared__ unsigned short Ah[2][128 * LDA], Aw[2][128 * LDA];
    __shared__ unsigned short Bh[2][64 * LDA],  Bw[2][64 * LDA];
    int tid = threadIdx.x, lane = tid & 63, wid = tid >> 6;
    int m0 = blockIdx.x * 128, n0 = blockIdx.y * 64;
    int wm = wid * 32;
    int arow0 = tid >> 2, arow1 = (256 + tid) >> 2, akc = (tid & 3) * 8;
    bool bok = (n0 + arow0) < KP;
    f32x4 acc[2][4] = {};
    bf16x8 rah0, rah1, ral0, ral1, rbh, rbl;
    const bf16x8 zero8 = {};

    rah0 = *(const bf16x8*)&Ahi_[(size_t)(m0 + arow0) * KP + akc];
    rah1 = *(const bf16x8*)&Ahi_[(size_t)(m0 + arow1) * KP + akc];
    ral0 = *(const bf16x8*)&Alo_[(size_t)(m0 + arow0) * KP + akc];
    ral1 = *(const bf16x8*)&Alo_[(size_t)(m0 + arow1) * KP + akc];
    rbh = bok ? *(const bf16x8*)&Whi_[(size_t)(n0 + arow0) * KP + akc] : zero8;
    rbl = bok ? *(const bf16x8*)&Wlo_[(size_t)(n0 + arow0) * KP + akc] : zero8;
    *(bf16x8*)&Ah[0][arow0 * LDA + akc] = rah0;
    *(bf16x8*)&Ah[0][arow1 * LDA + akc] = rah1;
    *(bf16x8*)&Aw[0][arow0 * LDA + akc] = ral0;
    *(bf16x8*)&Aw[0][arow1 * LDA + akc] = ral1;
    *(bf16x8*)&Bh[0][arow0 * LDA + akc] = rbh;
    *(bf16x8*)&Bw[0][arow0 * LDA + akc] = rbl;
    __syncthreads();

    int kk = (lane >> 4) * 8, cc = lane & 15;
    for (int kt = 0; kt < 17; kt++) {
        int cur = kt & 1;
        if (kt < 16) {
            int k0 = (kt + 1) * 32;
            rah0 = *(const bf16x8*)&Ahi_[(size_t)(m0 + arow0) * KP + k0 + akc];
            rah1 = *(const bf16x8*)&Ahi_[(size_t)(m0 + arow1) * KP + k0 + akc];
            ral0 = *(const bf16x8*)&Alo_[(size_t)(m0 + arow0) * KP + k0 + akc];
            ral1 = *(const bf16x8*)&Alo_[(size_t)(m0 + arow1) * KP + k0 + akc];
            rbh = bok ? *(const bf16x8*)&Whi_[(size_t)(n0 + arow0) * KP + k0 + akc] : zero8;
            rbl = bok ? *(const bf16x8*)&Wlo_[(size_t)(n0 + arow0) * KP + k0 + akc] : zero8;
        }
        bf16x8 ah[2], al[2], bh[4], bl[4];
#pragma unroll
        for (int mi = 0; mi < 2; mi++) {
            ah[mi] = *(const bf16x8*)&Ah[cur][(wm + mi * 16 + cc) * LDA + kk];
            al[mi] = *(const bf16x8*)&Aw[cur][(wm + mi * 16 + cc) * LDA + kk];
        }
#pragma unroll
        for (int ni = 0; ni < 4; ni++) {
            bh[ni] = *(const bf16x8*)&Bh[cur][(ni * 16 + cc) * LDA + kk];
            bl[ni] = *(const bf16x8*)&Bw[cur][(ni * 16 + cc) * LDA + kk];
        }
#pragma unroll
        for (int mi = 0; mi < 2; mi++)
#pragma unroll
            for (int ni = 0; ni < 4; ni++) {
                acc[mi][ni] = __builtin_amdgcn_mfma_f32_16x16x32_bf16(ah[mi], bh[ni], acc[mi][ni], 0, 0, 0);
                acc[mi][ni] = __builtin_amdgcn_mfma_f32_16x16x32_bf16(ah[mi], bl[ni], acc[mi][ni], 0, 0, 0);
                acc[mi][ni] = __builtin_amdgcn_mfma_f32_16x16x32_bf16(al[mi], bh[ni], acc[mi][ni], 0, 0, 0);
            }
        if (kt < 16) {
            int nxt = cur ^ 1;
            *(bf16x8*)&Ah[nxt][arow0 * LDA + akc] = rah0;
            *(bf16x8*)&Ah[nxt][arow1 * LDA + akc] = rah1;
            *(bf16x8*)&Aw[nxt][arow0 * LDA + akc] = ral0;
            *(bf16x8*)&Aw[nxt][arow1 * LDA + akc] = ral1;
            *(bf16x8*)&Bh[nxt][arow0 * LDA + akc] = rbh;
            *(bf16x8*)&Bw[nxt][arow0 * LDA + akc] = rbl;
        }
        __syncthreads();
    }
#pragma unroll
    for (int mi = 0; mi < 2; mi++)
#pragma unroll
        for (int ni = 0; ni < 4; ni++)
#pragma unroll
            for (int r = 0; r < 4; r++) {
                int row = m0 + wm + mi * 16 + (lane >> 4) * 4 + r;
                int col = n0 + ni * 16 + cc;
                if (col < C) out[(size_t)row * C + col] = acc[mi][ni][r] + bias[col];
            }
}

extern "C" void kernel_launch(void* const* d_in, const int* in_sizes, int n_in,
                              void* d_out, int out_size, void* d_ws, size_t ws_size,
                              hipStream_t stream) {
    const float* x      = (const float*)d_in[0];
    const float* w_qkv  = (const float*)d_in[1];
    const float* b_qkv  = (const float*)d_in[2];
    const float* w_proj = (const float*)d_in[3];
    const float* b_proj = (const float*)d_in[4];
    float* out = (float*)d_out;
    char* ws = (char*)d_ws;

    const size_t o_xb    = 0;
    const size_t o_wqkvb = o_xb    + 4456448;
    const size_t o_whi   = o_wqkvb + 1775616;
    const size_t o_wlo   = o_whi   + 591872;
    const size_t o_vtmp  = o_wlo   + 591872;
    const size_t o_qbf   = o_vtmp  + 4456448;
    const size_t o_kbf   = o_qbf   + 6291456;
    const size_t o_vt    = o_kbf   + 6291456;
    const size_t need    = o_vt + 6291456;
    if (ws_size < need) return;

    unsigned short* xb    = (unsigned short*)(ws + o_xb);
    unsigned short* wqkvb = (unsigned short*)(ws + o_wqkvb);
    unsigned short* whi   = (unsigned short*)(ws + o_whi);
    unsigned short* wlo   = (unsigned short*)(ws + o_wlo);
    unsigned short* vtmp  = (unsigned short*)(ws + o_vtmp);
    unsigned short* qbf   = (unsigned short*)(ws + o_qbf);
    unsigned short* kbf   = (unsigned short*)(ws + o_kbf);
    unsigned short* vt    = (unsigned short*)(ws + o_vt);
    unsigned short* ahi   = xb;
    unsigned short* alo   = vtmp;

    k_prep_all  <<<2048, 256, 0, stream>>>(x, w_qkv, w_proj, xb, wqkvb, whi, wlo, qbf, kbf);
    k_gemm_qkv  <<<dim3(N_TOK / 128, NQKVP / 96), 256, 0, stream>>>(xb, wqkvb, b_qkv, qbf, kbf, vtmp);
    k_reshape_v <<<dim3(N_TOK / 64, NH), 256, 0, stream>>>(vtmp, vt);
    k_attn      <<<dim3(256), 512, 0, stream>>>(qbf, kbf, vt, ahi, alo);
    k_gemm_proj <<<dim3(N_TOK / 128, 9), 256, 0, stream>>>(ahi, alo, whi, wlo, b_proj, out);
}